// Round 1
// baseline (3000.151 us; speedup 1.0000x reference)
//
#include <hip/hip_runtime.h>
#include <stdint.h>
#include <math.h>

#define DIM 3072
#define SEQ 4096
#define NH 24
#define HD 128
#define MLP 9216
#define FUSED 27648   // 3*DIM + 2*MLP
#define SD FUSED      // row stride of qkv_mlp buffer

typedef __attribute__((ext_vector_type(8))) short short8;
typedef __attribute__((ext_vector_type(4))) float f32x4;

__device__ __forceinline__ float bf2f(uint16_t b){ uint32_t x = ((uint32_t)b)<<16; return __builtin_bit_cast(float,x); }
__device__ __forceinline__ uint16_t f2bf(float f){
  uint32_t x = __builtin_bit_cast(uint32_t,f);
  x += 0x7fffu + ((x>>16)&1u);
  return (uint16_t)(x>>16);
}
__device__ __forceinline__ void gl_lds16(const void* g, void* l){
  __builtin_amdgcn_global_load_lds((const __attribute__((address_space(1))) void*)g,
                                   (__attribute__((address_space(3))) void*)l, 16, 0, 0);
}

// ---------------- transpose + cast fp32[K,N] -> bf16[N,K] ----------------
__global__ __launch_bounds__(256) void castT_kernel(const float* __restrict__ src,
                                                    uint16_t* __restrict__ dst, int K, int N){
  __shared__ float tile[32][33];
  int tx = threadIdx.x & 31, ty = threadIdx.x >> 5;
  int n0 = blockIdx.x<<5, k0 = blockIdx.y<<5;
  #pragma unroll
  for (int i=0;i<4;i++) tile[ty + i*8][tx] = src[(size_t)(k0 + ty + i*8)*N + n0 + tx];
  __syncthreads();
  #pragma unroll
  for (int i=0;i<4;i++) dst[(size_t)(n0 + ty + i*8)*K + k0 + tx] = f2bf(tile[tx][ty + i*8]);
}

// ---------------- LayerNorm + modulation -> bf16 h ----------------
__global__ __launch_bounds__(256) void ln_mod_kernel(const float* __restrict__ x,
                                                     const float* __restrict__ temb,
                                                     uint16_t* __restrict__ h){
  int s = blockIdx.x;
  int t = threadIdx.x;
  const float4* row = (const float4*)(x + (size_t)s*DIM);
  float4 v[3];
  float sum=0.f, ss=0.f;
  #pragma unroll
  for (int i=0;i<3;i++){
    v[i] = row[t + i*256];
    sum += v[i].x+v[i].y+v[i].z+v[i].w;
    ss  += v[i].x*v[i].x + v[i].y*v[i].y + v[i].z*v[i].z + v[i].w*v[i].w;
  }
  #pragma unroll
  for (int off=32; off; off>>=1){ sum += __shfl_xor(sum, off, 64); ss += __shfl_xor(ss, off, 64); }
  __shared__ float red[8];
  int lane = t&63, w = t>>6;
  if (lane==0){ red[w]=sum; red[w+4]=ss; }
  __syncthreads();
  sum = red[0]+red[1]+red[2]+red[3];
  ss  = red[4]+red[5]+red[6]+red[7];
  float mu = sum*(1.f/DIM);
  float var = ss*(1.f/DIM) - mu*mu;
  float rs = rsqrtf(var + 1e-6f);
  uint16_t* hrow = h + (size_t)s*DIM;
  #pragma unroll
  for (int i=0;i<3;i++){
    int c = (t + i*256)*4;
    float4 sc = *(const float4*)&temb[DIM + c];
    float4 sh = *(const float4*)&temb[c];
    ushort4 o;
    o.x = f2bf((v[i].x - mu)*rs*(1.f+sc.x) + sh.x);
    o.y = f2bf((v[i].y - mu)*rs*(1.f+sc.y) + sh.y);
    o.z = f2bf((v[i].z - mu)*rs*(1.f+sc.z) + sh.z);
    o.w = f2bf((v[i].w - mu)*rs*(1.f+sc.w) + sh.w);
    *(ushort4*)&hrow[c] = o;
  }
}

// ---------------- GEMM: C[M,N] = A[M,K] * BT[N,K]^T  (m97-style) ----------------
template<bool OUT_BF16, bool ACCUM>
__global__ __launch_bounds__(256) void gemm_bt_kernel(const uint16_t* __restrict__ A,
                                                      const uint16_t* __restrict__ BT,
                                                      void* __restrict__ Cout,
                                                      const float* __restrict__ Cadd,
                                                      int M, int N, int K){
  __shared__ alignas(16) uint16_t As[128*32];
  __shared__ alignas(16) uint16_t Bs[128*32];
  int mt = M>>7;
  int b = blockIdx.x;
  int panel = b/(mt<<3);
  int rem = b - panel*(mt<<3);
  size_t n0 = (size_t)(panel*8 + (rem&7))<<7;
  size_t m0 = (size_t)(rem>>3)<<7;
  int t = threadIdx.x, lane = t&63;
  int w = t>>6, wm = (w>>1)<<6, wn = (w&1)<<6;
  int lr = lane&15, lk = (lane>>4)<<3;
  const uint16_t* Ab = A + m0*(size_t)K;
  const uint16_t* Bb = BT + n0*(size_t)K;
  int c0 = t, c1 = t+256;
  const char* ga0 = (const char*)(Ab + (size_t)(c0>>2)*K) + ((c0&3)<<4);
  const char* ga1 = (const char*)(Ab + (size_t)(c1>>2)*K) + ((c1&3)<<4);
  const char* gb0 = (const char*)(Bb + (size_t)(c0>>2)*K) + ((c0&3)<<4);
  const char* gb1 = (const char*)(Bb + (size_t)(c1>>2)*K) + ((c1&3)<<4);
  char* la0 = (char*)As + c0*16; char* la1 = (char*)As + c1*16;
  char* lb0 = (char*)Bs + c0*16; char* lb1 = (char*)Bs + c1*16;
  f32x4 acc[4][4] = {};
  for (int k0=0; k0<K; k0+=32){
    __syncthreads();
    gl_lds16(ga0, la0); gl_lds16(ga1, la1);
    gl_lds16(gb0, lb0); gl_lds16(gb1, lb1);
    ga0 += 64; ga1 += 64; gb0 += 64; gb1 += 64;
    __syncthreads();
    short8 af[4], bf[4];
    #pragma unroll
    for (int mi=0;mi<4;mi++) af[mi] = *(const short8*)&As[(wm + mi*16 + lr)*32 + lk];
    #pragma unroll
    for (int ni=0;ni<4;ni++) bf[ni] = *(const short8*)&Bs[(wn + ni*16 + lr)*32 + lk];
    #pragma unroll
    for (int mi=0;mi<4;mi++)
      #pragma unroll
      for (int ni=0;ni<4;ni++)
        acc[mi][ni] = __builtin_amdgcn_mfma_f32_16x16x32_bf16(af[mi], bf[ni], acc[mi][ni], 0,0,0);
  }
  int qr = (lane>>4)<<2;
  #pragma unroll
  for (int mi=0;mi<4;mi++)
    #pragma unroll
    for (int ni=0;ni<4;ni++){
      size_t col = n0 + wn + ni*16 + lr;
      #pragma unroll
      for (int r=0;r<4;r++){
        size_t row = m0 + wm + mi*16 + qr + r;
        size_t idx = row*(size_t)N + col;
        float vv = acc[mi][ni][r];
        if (ACCUM) vv += Cadd[idx];
        if (OUT_BF16) ((uint16_t*)Cout)[idx] = f2bf(vv);
        else          ((float*)Cout)[idx] = vv;
      }
    }
}

// ---------------- per-head RMSNorm + RoPE on q,k (in place) ----------------
__global__ __launch_bounds__(256) void qk_rope_kernel(uint16_t* __restrict__ qkv,
                                                      const float* __restrict__ cosb,
                                                      const float* __restrict__ sinb,
                                                      const float* __restrict__ wq,
                                                      const float* __restrict__ wk){
  int t = threadIdx.x, lane = t&63, w = t>>6;
  int pair = blockIdx.x*4 + w;
  int s = pair/24, hh = pair - s*24;
  int d0 = lane*2;
  float c0 = cosb[s*HD + d0], c1 = cosb[s*HD + d0+1];
  float sn0 = sinb[s*HD + d0], sn1 = sinb[s*HD + d0+1];
  #pragma unroll
  for (int which=0; which<2; ++which){
    uint16_t* p = qkv + (size_t)s*SD + which*DIM + hh*HD + d0;
    const float* ww = which ? wk : wq;
    uint32_t u = *(const uint32_t*)p;
    float x0 = bf2f((uint16_t)(u&0xffffu)), x1 = bf2f((uint16_t)(u>>16));
    float ssum = x0*x0 + x1*x1;
    #pragma unroll
    for (int off=32; off; off>>=1) ssum += __shfl_xor(ssum, off, 64);
    float r = rsqrtf(ssum*(1.f/HD) + 1e-6f);
    float xn0 = x0*r*ww[d0], xn1 = x1*r*ww[d0+1];
    float y0 = xn0*c0 - xn1*sn0;
    float y1 = xn1*c1 + xn0*sn1;
    *(uint32_t*)p = (uint32_t)f2bf(y0) | ((uint32_t)f2bf(y1)<<16);
  }
}

// ---------------- flash attention ----------------
__global__ __launch_bounds__(256) void attn_kernel(const uint16_t* __restrict__ qkv,
                                                   uint16_t* __restrict__ out){
  __shared__ alignas(16) uint16_t QP[64*128];   // Q staging, then per-wave P (swizzled)
  __shared__ alignas(16) uint16_t Ks[64*128];   // [key][d], d-granule swizzled by key&15
  __shared__ alignas(16) uint16_t Vt[128*64];   // [d][key], key-granule swizzled by (d>>1)&7
  int t = threadIdx.x, lane = t&63, w = t>>6;
  int q0 = blockIdx.x<<6, h = blockIdx.y;
  int lr = lane&15, q4 = lane>>4, lk = q4<<3;
  const uint16_t* qb = qkv + (size_t)q0*SD + h*HD;
  #pragma unroll
  for (int i=0;i<4;i++){
    int c = t + i*256;
    gl_lds16((const char*)(qb + (size_t)(c>>4)*SD) + ((c&15)<<4), (char*)QP + c*16);
  }
  __syncthreads();
  short8 qf[4];
  #pragma unroll
  for (int kc=0;kc<4;kc++) qf[kc] = *(const short8*)&QP[(w*16+lr)*128 + kc*32 + lk];
  __syncthreads();   // QP now reusable as P scratch
  float m_i[4] = {-3.0e38f,-3.0e38f,-3.0e38f,-3.0e38f};
  float l_i[4] = {0.f,0.f,0.f,0.f};
  f32x4 o[8] = {};
  const uint16_t* kb = qkv + (size_t)DIM + h*HD;
  const uint16_t* vb = qkv + (size_t)(2*DIM) + h*HD;
  uint16_t* Pw = QP + w*(16*64);
  const float scale = 0.08838834764831845f;
  for (int kt=0; kt<64; ++kt){
    const uint16_t* kbt = kb + (size_t)(kt<<6)*SD;
    const uint16_t* vbt = vb + (size_t)(kt<<6)*SD;
    __syncthreads();
    #pragma unroll
    for (int i=0;i<4;i++){          // K tile, swizzled
      int c = t + i*256;
      int row = c>>4, gd = c&15;
      uint4 vv = *(const uint4*)(kbt + (size_t)row*SD + gd*8);
      *(uint4*)&Ks[row*128 + ((gd ^ (row&15))<<3)] = vv;
    }
    #pragma unroll
    for (int i=0;i<8;i++){          // V tile, transposed + swizzled
      int idx = t + i*256;
      int rp = idx>>6;
      int k0 = rp<<1, d0 = lane<<1;
      uint32_t u0 = *(const uint32_t*)(vbt + (size_t)k0*SD + d0);
      uint32_t u1 = *(const uint32_t*)(vbt + (size_t)(k0+1)*SD + d0);
      int pos = (((rp>>2) ^ (lane&7))<<3) + (k0&7);
      *(uint32_t*)&Vt[(d0<<6) + pos]     = (u0&0xffffu) | (u1<<16);
      *(uint32_t*)&Vt[((d0+1)<<6) + pos] = (u0>>16) | (u1&0xffff0000u);
    }
    __syncthreads();
    f32x4 sa[4];
    #pragma unroll
    for (int nk=0;nk<4;nk++){
      sa[nk] = (f32x4){0.f,0.f,0.f,0.f};
      #pragma unroll
      for (int kc=0;kc<4;kc++){
        short8 kf = *(const short8*)&Ks[(nk*16+lr)*128 + (((kc*4+q4) ^ lr)<<3)];
        sa[nk] = __builtin_amdgcn_mfma_f32_16x16x32_bf16(qf[kc], kf, sa[nk], 0,0,0);
      }
      sa[nk] *= scale;
    }
    float alpha[4], psum[4];
    #pragma unroll
    for (int r=0;r<4;r++){
      float mx = fmaxf(fmaxf(sa[0][r], sa[1][r]), fmaxf(sa[2][r], sa[3][r]));
      mx = fmaxf(mx, __shfl_xor(mx, 1, 64));
      mx = fmaxf(mx, __shfl_xor(mx, 2, 64));
      mx = fmaxf(mx, __shfl_xor(mx, 4, 64));
      mx = fmaxf(mx, __shfl_xor(mx, 8, 64));
      float mn = fmaxf(m_i[r], mx);
      alpha[r] = __expf(m_i[r] - mn);
      m_i[r] = mn;
      psum[r] = 0.f;
    }
    int prow = q4<<2;
    #pragma unroll
    for (int nk=0;nk<4;nk++){
      #pragma unroll
      for (int r=0;r<4;r++){
        float p = __expf(sa[nk][r] - m_i[r]);
        psum[r] += p;
        int key = nk*16 + lr;
        Pw[(prow+r)*64 + ((((key>>3) ^ (prow+r))&7)<<3) + (key&7)] = f2bf(p);
      }
    }
    #pragma unroll
    for (int r=0;r<4;r++){
      float ps = psum[r];
      ps += __shfl_xor(ps, 1, 64);
      ps += __shfl_xor(ps, 2, 64);
      ps += __shfl_xor(ps, 4, 64);
      ps += __shfl_xor(ps, 8, 64);
      l_i[r] = l_i[r]*alpha[r] + ps;
    }
    #pragma unroll
    for (int nd=0;nd<8;nd++){
      f32x4 t4 = o[nd];
      t4[0]*=alpha[0]; t4[1]*=alpha[1]; t4[2]*=alpha[2]; t4[3]*=alpha[3];
      o[nd]=t4;
    }
    #pragma unroll
    for (int kc=0;kc<2;kc++){
      short8 pf = *(const short8*)&Pw[lr*64 + ((((kc*4+q4) ^ lr)&7)<<3)];
      #pragma unroll
      for (int nd=0;nd<8;nd++){
        int d = nd*16 + lr;
        short8 vf = *(const short8*)&Vt[(d<<6) + ((((kc*4+q4) ^ ((lr>>1)&7)))<<3)];
        o[nd] = __builtin_amdgcn_mfma_f32_16x16x32_bf16(pf, vf, o[nd], 0,0,0);
      }
    }
  }
  uint16_t* ob = out + (size_t)(q0 + w*16)*DIM + h*HD;
  #pragma unroll
  for (int r=0;r<4;r++){
    float inv = 1.f/l_i[r];
    #pragma unroll
    for (int nd=0;nd<8;nd++)
      ob[(size_t)(q4*4 + r)*DIM + nd*16 + lr] = f2bf(o[nd][r]*inv);
  }
}

// ---------------- SwiGLU ----------------
__global__ __launch_bounds__(256) void swiglu_kernel(const uint16_t* __restrict__ qkv,
                                                     uint16_t* __restrict__ mlp){
  size_t idx = ((size_t)blockIdx.x*256 + threadIdx.x)*4;
  size_t s = idx/MLP, j = idx - s*MLP;
  const uint16_t* pa = qkv + s*SD + 3*DIM + j;
  const uint16_t* pb = pa + MLP;
  ushort4 ua = *(const ushort4*)pa, ub = *(const ushort4*)pb;
  ushort4 o;
  float a, b;
  a = bf2f(ua.x); b = bf2f(ub.x); o.x = f2bf(a*b/(1.f+__expf(-a)));
  a = bf2f(ua.y); b = bf2f(ub.y); o.y = f2bf(a*b/(1.f+__expf(-a)));
  a = bf2f(ua.z); b = bf2f(ub.z); o.z = f2bf(a*b/(1.f+__expf(-a)));
  a = bf2f(ua.w); b = bf2f(ub.w); o.w = f2bf(a*b/(1.f+__expf(-a)));
  *(ushort4*)(mlp + s*MLP + j) = o;
}

// ---------------- residual + gate ----------------
__global__ __launch_bounds__(256) void final_kernel(const float* __restrict__ resid,
                                                    const float* __restrict__ temb,
                                                    const float* __restrict__ c2,
                                                    float* __restrict__ outp){
  size_t i4 = (size_t)blockIdx.x*256 + threadIdx.x;
  float4 r = ((const float4*)resid)[i4];
  float4 c = ((const float4*)c2)[i4];
  size_t d = (i4 % (DIM/4))*4;
  const float* g = temb + 2*DIM + d;
  float4 o;
  o.x = r.x + g[0]*c.x; o.y = r.y + g[1]*c.y;
  o.z = r.z + g[2]*c.z; o.w = r.w + g[3]*c.w;
  ((float4*)outp)[i4] = o;
}

extern "C" void kernel_launch(void* const* d_in, const int* in_sizes, int n_in,
                              void* d_out, int out_size, void* d_ws, size_t ws_size,
                              hipStream_t stream){
  (void)in_sizes; (void)n_in; (void)out_size;
  const float* hs   = (const float*)d_in[0];
  const float* temb = (const float*)d_in[1];
  const float* rcos = (const float*)d_in[2];
  const float* rsin = (const float*)d_in[3];
  const float* w1   = (const float*)d_in[4];
  const float* wa   = (const float*)d_in[5];
  const float* wm   = (const float*)d_in[6];
  const float* nqw  = (const float*)d_in[7];
  const float* nkw  = (const float*)d_in[8];

  char* ws = (char*)d_ws;
  const size_t off_w1T  = 0;               // 27648x3072 bf16 = 169869312
  const size_t off_waT  = 169869312ULL;    // 3072x3072  bf16 = 18874368
  const size_t off_wmT  = 188743680ULL;    // 3072x9216  bf16 = 56623104
  const size_t off_h    = 245366784ULL;    // 4096x3072  bf16 = 25165824
  const size_t off_qkv  = 270532608ULL;    // 4096x27648 bf16 = 226492416
  const size_t off_attn = 497025024ULL;    // 4096x3072  bf16 = 25165824
  const size_t off_mlp  = 522190848ULL;    // 4096x9216  bf16 = 75497472
  const size_t off_c2   = 597688320ULL;    // 4096x3072  f32  = 50331648
  const size_t needed   = 648019968ULL;
  if (ws_size < needed) return;  // workspace too small: fail loudly (zero output)

  uint16_t* w1T  = (uint16_t*)(ws + off_w1T);
  uint16_t* waT  = (uint16_t*)(ws + off_waT);
  uint16_t* wmT  = (uint16_t*)(ws + off_wmT);
  uint16_t* hbuf = (uint16_t*)(ws + off_h);
  uint16_t* qkv  = (uint16_t*)(ws + off_qkv);
  uint16_t* attn = (uint16_t*)(ws + off_attn);
  uint16_t* mlpb = (uint16_t*)(ws + off_mlp);
  float*    c2   = (float*)(ws + off_c2);

  castT_kernel<<<dim3(FUSED/32, DIM/32), 256, 0, stream>>>(w1, w1T, DIM, FUSED);
  castT_kernel<<<dim3(DIM/32,  DIM/32),  256, 0, stream>>>(wa, waT, DIM, DIM);
  castT_kernel<<<dim3(DIM/32,  MLP/32),  256, 0, stream>>>(wm, wmT, MLP, DIM);
  ln_mod_kernel<<<SEQ, 256, 0, stream>>>(hs, temb, hbuf);
  gemm_bt_kernel<true,false><<<(SEQ/128)*(FUSED/128), 256, 0, stream>>>(hbuf, w1T, qkv, nullptr, SEQ, FUSED, DIM);
  qk_rope_kernel<<<SEQ*NH/4, 256, 0, stream>>>(qkv, rcos, rsin, nqw, nkw);
  attn_kernel<<<dim3(SEQ/64, NH), 256, 0, stream>>>(qkv, attn);
  swiglu_kernel<<<(SEQ*(size_t)MLP/4)/256, 256, 0, stream>>>(qkv, mlpb);
  gemm_bt_kernel<false,false><<<(SEQ/128)*(DIM/128), 256, 0, stream>>>(attn, waT, c2, nullptr, SEQ, DIM, DIM);
  gemm_bt_kernel<false,true><<<(SEQ/128)*(DIM/128), 256, 0, stream>>>(mlpb, wmT, c2, c2, SEQ, DIM, MLP);
  final_kernel<<<(SEQ*(size_t)DIM/4)/256, 256, 0, stream>>>(hs, temb, c2, (float*)d_out);
}

// Round 2
// 2996.208 us; speedup vs baseline: 1.0013x; 1.0013x over previous
//
#include <hip/hip_runtime.h>
#include <stdint.h>
#include <math.h>

#define DIM 3072
#define SEQ 4096
#define NH 24
#define HD 128
#define MLP 9216
#define FUSED 27648   // 3*DIM + 2*MLP
#define SD FUSED      // row stride of qkv_mlp buffer
#define K2 12288      // fused output-GEMM K (DIM + MLP)

typedef __attribute__((ext_vector_type(8))) short short8;
typedef __attribute__((ext_vector_type(4))) float f32x4;

__device__ __forceinline__ float bf2f(uint16_t b){ uint32_t x = ((uint32_t)b)<<16; return __builtin_bit_cast(float,x); }
__device__ __forceinline__ uint16_t f2bf(float f){
  uint32_t x = __builtin_bit_cast(uint32_t,f);
  x += 0x7fffu + ((x>>16)&1u);
  return (uint16_t)(x>>16);
}
__device__ __forceinline__ void gl_lds16(const void* g, void* l){
  __builtin_amdgcn_global_load_lds((const __attribute__((address_space(1))) void*)g,
                                   (__attribute__((address_space(3))) void*)l, 16, 0, 0);
}

// ---------------- transpose + cast fp32[K,N] -> bf16[N,:] at dst[n*dstStride + k] ----------------
__global__ __launch_bounds__(256) void castT_kernel(const float* __restrict__ src,
                                                    uint16_t* __restrict__ dst,
                                                    int K, int N, int dstStride){
  __shared__ float tile[32][33];
  int t = threadIdx.x;
  int n0 = blockIdx.x<<5, k0 = blockIdx.y<<5;
  int r = t>>3, c4 = (t&7)<<2;
  float4 v = *(const float4*)&src[(size_t)(k0+r)*N + n0 + c4];
  tile[r][c4] = v.x; tile[r][c4+1] = v.y; tile[r][c4+2] = v.z; tile[r][c4+3] = v.w;
  __syncthreads();
  int n = t>>3, kc = (t&7)<<2;
  ushort4 o;
  o.x = f2bf(tile[kc  ][n]);
  o.y = f2bf(tile[kc+1][n]);
  o.z = f2bf(tile[kc+2][n]);
  o.w = f2bf(tile[kc+3][n]);
  *(ushort4*)&dst[(size_t)(n0+n)*dstStride + k0 + kc] = o;
}

// ---------------- LayerNorm + modulation -> bf16 h ----------------
__global__ __launch_bounds__(256) void ln_mod_kernel(const float* __restrict__ x,
                                                     const float* __restrict__ temb,
                                                     uint16_t* __restrict__ h){
  int s = blockIdx.x;
  int t = threadIdx.x;
  const float4* row = (const float4*)(x + (size_t)s*DIM);
  float4 v[3];
  float sum=0.f, ss=0.f;
  #pragma unroll
  for (int i=0;i<3;i++){
    v[i] = row[t + i*256];
    sum += v[i].x+v[i].y+v[i].z+v[i].w;
    ss  += v[i].x*v[i].x + v[i].y*v[i].y + v[i].z*v[i].z + v[i].w*v[i].w;
  }
  #pragma unroll
  for (int off=32; off; off>>=1){ sum += __shfl_xor(sum, off, 64); ss += __shfl_xor(ss, off, 64); }
  __shared__ float red[8];
  int lane = t&63, w = t>>6;
  if (lane==0){ red[w]=sum; red[w+4]=ss; }
  __syncthreads();
  sum = red[0]+red[1]+red[2]+red[3];
  ss  = red[4]+red[5]+red[6]+red[7];
  float mu = sum*(1.f/DIM);
  float var = ss*(1.f/DIM) - mu*mu;
  float rs = rsqrtf(var + 1e-6f);
  uint16_t* hrow = h + (size_t)s*DIM;
  #pragma unroll
  for (int i=0;i<3;i++){
    int c = (t + i*256)*4;
    float4 sc = *(const float4*)&temb[DIM + c];
    float4 sh = *(const float4*)&temb[c];
    ushort4 o;
    o.x = f2bf((v[i].x - mu)*rs*(1.f+sc.x) + sh.x);
    o.y = f2bf((v[i].y - mu)*rs*(1.f+sc.y) + sh.y);
    o.z = f2bf((v[i].z - mu)*rs*(1.f+sc.z) + sh.z);
    o.w = f2bf((v[i].w - mu)*rs*(1.f+sc.w) + sh.w);
    *(ushort4*)&hrow[c] = o;
  }
}

// ---------------- GEMM: C[M,N] = A[M,K] * BT[N,K]^T  (m97-style + XOR-swizzled LDS) ----------------
// FINAL epilogue: out[idx] = resid[idx] + gate[col]*acc   (fp32 out)
template<bool OUT_BF16, bool FINAL>
__global__ __launch_bounds__(256) void gemm_bt_kernel(const uint16_t* __restrict__ A,
                                                      const uint16_t* __restrict__ BT,
                                                      void* __restrict__ Cout,
                                                      const float* __restrict__ resid,
                                                      const float* __restrict__ temb,
                                                      int M, int N, int K){
  __shared__ alignas(16) uint16_t As[128*32];
  __shared__ alignas(16) uint16_t Bs[128*32];
  int mt = M>>7;
  int b = blockIdx.x;
  int panel = b/(mt<<3);
  int rem = b - panel*(mt<<3);
  size_t n0 = (size_t)(panel*8 + (rem&7))<<7;
  size_t m0 = (size_t)(rem>>3)<<7;
  int t = threadIdx.x, lane = t&63;
  int w = t>>6, wm = (w>>1)<<6, wn = (w&1)<<6;
  int lr = lane&15, q4 = lane>>4;
  int swl = (lr ^ (lr>>2)) & 3;             // fragment-read swizzle (row bits from lr)
  const uint16_t* Ab = A + m0*(size_t)K;
  const uint16_t* Bb = BT + n0*(size_t)K;
  int c0 = t, c1 = t+256;
  int r0 = c0>>2, r1 = c1>>2;
  int j0 = (c0&3) ^ ((r0 ^ (r0>>2))&3);     // staged global chunk for LDS slot c0
  int j1 = (c1&3) ^ ((r1 ^ (r1>>2))&3);
  const char* ga0 = (const char*)(Ab + (size_t)r0*K) + (j0<<4);
  const char* ga1 = (const char*)(Ab + (size_t)r1*K) + (j1<<4);
  const char* gb0 = (const char*)(Bb + (size_t)r0*K) + (j0<<4);
  const char* gb1 = (const char*)(Bb + (size_t)r1*K) + (j1<<4);
  char* la0 = (char*)As + c0*16; char* la1 = (char*)As + c1*16;
  char* lb0 = (char*)Bs + c0*16; char* lb1 = (char*)Bs + c1*16;
  f32x4 acc[4][4] = {};
  for (int k0=0; k0<K; k0+=32){
    __syncthreads();
    gl_lds16(ga0, la0); gl_lds16(ga1, la1);
    gl_lds16(gb0, lb0); gl_lds16(gb1, lb1);
    ga0 += 64; ga1 += 64; gb0 += 64; gb1 += 64;
    __syncthreads();
    short8 af[4], bf[4];
    #pragma unroll
    for (int mi=0;mi<4;mi++) af[mi] = *(const short8*)&As[(wm + mi*16 + lr)*32 + ((q4 ^ swl)<<3)];
    #pragma unroll
    for (int ni=0;ni<4;ni++) bf[ni] = *(const short8*)&Bs[(wn + ni*16 + lr)*32 + ((q4 ^ swl)<<3)];
    #pragma unroll
    for (int mi=0;mi<4;mi++)
      #pragma unroll
      for (int ni=0;ni<4;ni++)
        acc[mi][ni] = __builtin_amdgcn_mfma_f32_16x16x32_bf16(af[mi], bf[ni], acc[mi][ni], 0,0,0);
  }
  int qr = q4<<2;
  #pragma unroll
  for (int mi=0;mi<4;mi++)
    #pragma unroll
    for (int ni=0;ni<4;ni++){
      size_t col = n0 + wn + ni*16 + lr;
      #pragma unroll
      for (int r=0;r<4;r++){
        size_t row = m0 + wm + mi*16 + qr + r;
        size_t idx = row*(size_t)N + col;
        float vv = acc[mi][ni][r];
        if (FINAL) vv = resid[idx] + temb[2*DIM + col]*vv;
        if (OUT_BF16) ((uint16_t*)Cout)[idx] = f2bf(vv);
        else          ((float*)Cout)[idx] = vv;
      }
    }
}

// ---------------- per-head RMSNorm + RoPE on q,k (in place) ----------------
__global__ __launch_bounds__(256) void qk_rope_kernel(uint16_t* __restrict__ qkv,
                                                      const float* __restrict__ cosb,
                                                      const float* __restrict__ sinb,
                                                      const float* __restrict__ wq,
                                                      const float* __restrict__ wk){
  int t = threadIdx.x, lane = t&63, w = t>>6;
  int pair = blockIdx.x*4 + w;
  int s = pair/24, hh = pair - s*24;
  int d0 = lane*2;
  float c0 = cosb[s*HD + d0], c1 = cosb[s*HD + d0+1];
  float sn0 = sinb[s*HD + d0], sn1 = sinb[s*HD + d0+1];
  #pragma unroll
  for (int which=0; which<2; ++which){
    uint16_t* p = qkv + (size_t)s*SD + which*DIM + hh*HD + d0;
    const float* ww = which ? wk : wq;
    uint32_t u = *(const uint32_t*)p;
    float x0 = bf2f((uint16_t)(u&0xffffu)), x1 = bf2f((uint16_t)(u>>16));
    float ssum = x0*x0 + x1*x1;
    #pragma unroll
    for (int off=32; off; off>>=1) ssum += __shfl_xor(ssum, off, 64);
    float r = rsqrtf(ssum*(1.f/HD) + 1e-6f);
    float xn0 = x0*r*ww[d0], xn1 = x1*r*ww[d0+1];
    float y0 = xn0*c0 - xn1*sn0;
    float y1 = xn1*c1 + xn0*sn1;
    *(uint32_t*)p = (uint32_t)f2bf(y0) | ((uint32_t)f2bf(y1)<<16);
  }
}

// ---------------- flash attention (out has row stride K2, cols 0..DIM-1) ----------------
__global__ __launch_bounds__(256) void attn_kernel(const uint16_t* __restrict__ qkv,
                                                   uint16_t* __restrict__ out){
  __shared__ alignas(16) uint16_t QP[64*128];   // Q staging, then per-wave P (swizzled)
  __shared__ alignas(16) uint16_t Ks[64*128];   // [key][d], d-granule swizzled by key&15
  __shared__ alignas(16) uint16_t Vt[128*64];   // [d][key], key-granule swizzled by (d>>1)&7
  int t = threadIdx.x, lane = t&63, w = t>>6;
  int q0 = blockIdx.x<<6, h = blockIdx.y;
  int lr = lane&15, q4 = lane>>4, lk = q4<<3;
  const uint16_t* qb = qkv + (size_t)q0*SD + h*HD;
  #pragma unroll
  for (int i=0;i<4;i++){
    int c = t + i*256;
    gl_lds16((const char*)(qb + (size_t)(c>>4)*SD) + ((c&15)<<4), (char*)QP + c*16);
  }
  __syncthreads();
  short8 qf[4];
  #pragma unroll
  for (int kc=0;kc<4;kc++) qf[kc] = *(const short8*)&QP[(w*16+lr)*128 + kc*32 + lk];
  __syncthreads();   // QP now reusable as P scratch
  float m_i[4] = {-3.0e38f,-3.0e38f,-3.0e38f,-3.0e38f};
  float l_i[4] = {0.f,0.f,0.f,0.f};
  f32x4 o[8] = {};
  const uint16_t* kb = qkv + (size_t)DIM + h*HD;
  const uint16_t* vb = qkv + (size_t)(2*DIM) + h*HD;
  uint16_t* Pw = QP + w*(16*64);
  const float scale = 0.08838834764831845f;
  for (int kt=0; kt<64; ++kt){
    const uint16_t* kbt = kb + (size_t)(kt<<6)*SD;
    const uint16_t* vbt = vb + (size_t)(kt<<6)*SD;
    __syncthreads();
    #pragma unroll
    for (int i=0;i<4;i++){          // K tile, swizzled
      int c = t + i*256;
      int row = c>>4, gd = c&15;
      uint4 vv = *(const uint4*)(kbt + (size_t)row*SD + gd*8);
      *(uint4*)&Ks[row*128 + ((gd ^ (row&15))<<3)] = vv;
    }
    #pragma unroll
    for (int i=0;i<8;i++){          // V tile, transposed + swizzled
      int idx = t + i*256;
      int rp = idx>>6;
      int k0 = rp<<1, d0 = lane<<1;
      uint32_t u0 = *(const uint32_t*)(vbt + (size_t)k0*SD + d0);
      uint32_t u1 = *(const uint32_t*)(vbt + (size_t)(k0+1)*SD + d0);
      int pos = (((rp>>2) ^ (lane&7))<<3) + (k0&7);
      *(uint32_t*)&Vt[(d0<<6) + pos]     = (u0&0xffffu) | (u1<<16);
      *(uint32_t*)&Vt[((d0+1)<<6) + pos] = (u0>>16) | (u1&0xffff0000u);
    }
    __syncthreads();
    f32x4 sa[4];
    #pragma unroll
    for (int nk=0;nk<4;nk++){
      sa[nk] = (f32x4){0.f,0.f,0.f,0.f};
      #pragma unroll
      for (int kc=0;kc<4;kc++){
        short8 kf = *(const short8*)&Ks[(nk*16+lr)*128 + (((kc*4+q4) ^ lr)<<3)];
        sa[nk] = __builtin_amdgcn_mfma_f32_16x16x32_bf16(qf[kc], kf, sa[nk], 0,0,0);
      }
      sa[nk] *= scale;
    }
    float alpha[4], psum[4];
    #pragma unroll
    for (int r=0;r<4;r++){
      float mx = fmaxf(fmaxf(sa[0][r], sa[1][r]), fmaxf(sa[2][r], sa[3][r]));
      mx = fmaxf(mx, __shfl_xor(mx, 1, 64));
      mx = fmaxf(mx, __shfl_xor(mx, 2, 64));
      mx = fmaxf(mx, __shfl_xor(mx, 4, 64));
      mx = fmaxf(mx, __shfl_xor(mx, 8, 64));
      float mn = fmaxf(m_i[r], mx);
      alpha[r] = __expf(m_i[r] - mn);
      m_i[r] = mn;
      psum[r] = 0.f;
    }
    int prow = q4<<2;
    #pragma unroll
    for (int nk=0;nk<4;nk++){
      #pragma unroll
      for (int r=0;r<4;r++){
        float p = __expf(sa[nk][r] - m_i[r]);
        psum[r] += p;
        int key = nk*16 + lr;
        Pw[(prow+r)*64 + ((((key>>3) ^ (prow+r))&7)<<3) + (key&7)] = f2bf(p);
      }
    }
    #pragma unroll
    for (int r=0;r<4;r++){
      float ps = psum[r];
      ps += __shfl_xor(ps, 1, 64);
      ps += __shfl_xor(ps, 2, 64);
      ps += __shfl_xor(ps, 4, 64);
      ps += __shfl_xor(ps, 8, 64);
      l_i[r] = l_i[r]*alpha[r] + ps;
    }
    #pragma unroll
    for (int nd=0;nd<8;nd++){
      f32x4 t4 = o[nd];
      t4[0]*=alpha[0]; t4[1]*=alpha[1]; t4[2]*=alpha[2]; t4[3]*=alpha[3];
      o[nd]=t4;
    }
    #pragma unroll
    for (int kc=0;kc<2;kc++){
      short8 pf = *(const short8*)&Pw[lr*64 + ((((kc*4+q4) ^ lr)&7)<<3)];
      #pragma unroll
      for (int nd=0;nd<8;nd++){
        int d = nd*16 + lr;
        short8 vf = *(const short8*)&Vt[(d<<6) + ((((kc*4+q4) ^ ((lr>>1)&7)))<<3)];
        o[nd] = __builtin_amdgcn_mfma_f32_16x16x32_bf16(pf, vf, o[nd], 0,0,0);
      }
    }
  }
  uint16_t* ob = out + (size_t)(q0 + w*16)*K2 + h*HD;
  #pragma unroll
  for (int r=0;r<4;r++){
    float inv = 1.f/l_i[r];
    #pragma unroll
    for (int nd=0;nd<8;nd++)
      ob[(size_t)(q4*4 + r)*K2 + nd*16 + lr] = f2bf(o[nd][r]*inv);
  }
}

// ---------------- SwiGLU (out has row stride K2, at col offset DIM) ----------------
__global__ __launch_bounds__(256) void swiglu_kernel(const uint16_t* __restrict__ qkv,
                                                     uint16_t* __restrict__ mlp){
  size_t idx = ((size_t)blockIdx.x*256 + threadIdx.x)*4;
  size_t s = idx/MLP, j = idx - s*MLP;
  const uint16_t* pa = qkv + s*SD + 3*DIM + j;
  const uint16_t* pb = pa + MLP;
  ushort4 ua = *(const ushort4*)pa, ub = *(const ushort4*)pb;
  ushort4 o;
  float a, b;
  a = bf2f(ua.x); b = bf2f(ub.x); o.x = f2bf(a*b/(1.f+__expf(-a)));
  a = bf2f(ua.y); b = bf2f(ub.y); o.y = f2bf(a*b/(1.f+__expf(-a)));
  a = bf2f(ua.z); b = bf2f(ub.z); o.z = f2bf(a*b/(1.f+__expf(-a)));
  a = bf2f(ua.w); b = bf2f(ub.w); o.w = f2bf(a*b/(1.f+__expf(-a)));
  *(ushort4*)(mlp + s*K2 + j) = o;
}

extern "C" void kernel_launch(void* const* d_in, const int* in_sizes, int n_in,
                              void* d_out, int out_size, void* d_ws, size_t ws_size,
                              hipStream_t stream){
  (void)in_sizes; (void)n_in; (void)out_size;
  const float* hs   = (const float*)d_in[0];
  const float* temb = (const float*)d_in[1];
  const float* rcos = (const float*)d_in[2];
  const float* rsin = (const float*)d_in[3];
  const float* w1   = (const float*)d_in[4];
  const float* wa   = (const float*)d_in[5];
  const float* wm   = (const float*)d_in[6];
  const float* nqw  = (const float*)d_in[7];
  const float* nkw  = (const float*)d_in[8];

  char* ws = (char*)d_ws;
  const size_t off_w1T  = 0;               // 27648x3072 bf16 = 169,869,312
  const size_t off_woT  = 169869312ULL;    // 3072x12288 bf16 =  75,497,472
  const size_t off_h    = 245366784ULL;    // 4096x3072  bf16 =  25,165,824
  const size_t off_qkv  = 270532608ULL;    // 4096x27648 bf16 = 226,492,416
  const size_t off_ap   = 497025024ULL;    // 4096x12288 bf16 = 100,663,296
  const size_t needed   = 597688320ULL;
  if (ws_size < needed) return;

  uint16_t* w1T  = (uint16_t*)(ws + off_w1T);
  uint16_t* woT  = (uint16_t*)(ws + off_woT);
  uint16_t* hbuf = (uint16_t*)(ws + off_h);
  uint16_t* qkv  = (uint16_t*)(ws + off_qkv);
  uint16_t* ap   = (uint16_t*)(ws + off_ap);   // [attn | swiglu] fused A'

  castT_kernel<<<dim3(FUSED/32, DIM/32), 256, 0, stream>>>(w1, w1T, DIM, FUSED, DIM);
  castT_kernel<<<dim3(DIM/32,  DIM/32),  256, 0, stream>>>(wa, woT, DIM, DIM, K2);
  castT_kernel<<<dim3(DIM/32,  MLP/32),  256, 0, stream>>>(wm, woT + DIM, MLP, DIM, K2);
  ln_mod_kernel<<<SEQ, 256, 0, stream>>>(hs, temb, hbuf);
  gemm_bt_kernel<true,false><<<(SEQ/128)*(FUSED/128), 256, 0, stream>>>(hbuf, w1T, qkv, nullptr, nullptr, SEQ, FUSED, DIM);
  qk_rope_kernel<<<SEQ*NH/4, 256, 0, stream>>>(qkv, rcos, rsin, nqw, nkw);
  attn_kernel<<<dim3(SEQ/64, NH), 256, 0, stream>>>(qkv, ap);
  swiglu_kernel<<<(SEQ*(size_t)MLP/4)/256, 256, 0, stream>>>(qkv, ap + DIM);
  gemm_bt_kernel<false,true><<<(SEQ/128)*(DIM/128), 256, 0, stream>>>(ap, woT, d_out, hs, temb, SEQ, DIM, K2);
}

// Round 3
// 2518.321 us; speedup vs baseline: 1.1913x; 1.1898x over previous
//
#include <hip/hip_runtime.h>
#include <stdint.h>
#include <math.h>

#define DIM 3072
#define SEQ 4096
#define NH 24
#define HD 128
#define MLP 9216
#define FUSED 27648   // 3*DIM + 2*MLP
#define SD FUSED      // row stride of qkv_mlp buffer
#define K2 12288      // fused output-GEMM K (DIM + MLP)

typedef __attribute__((ext_vector_type(8))) short short8;
typedef __attribute__((ext_vector_type(4))) float f32x4;

__device__ __forceinline__ float bf2f(uint16_t b){ uint32_t x = ((uint32_t)b)<<16; return __builtin_bit_cast(float,x); }
__device__ __forceinline__ uint16_t f2bf(float f){
  uint32_t x = __builtin_bit_cast(uint32_t,f);
  x += 0x7fffu + ((x>>16)&1u);
  return (uint16_t)(x>>16);
}
__device__ __forceinline__ void gl_lds16(const void* g, void* l){
  __builtin_amdgcn_global_load_lds((const __attribute__((address_space(1))) void*)g,
                                   (__attribute__((address_space(3))) void*)l, 16, 0, 0);
}

// ---------------- transpose + cast fp32[K,N] -> bf16[N,:] at dst[n*dstStride + k] ----------------
__global__ __launch_bounds__(256) void castT_kernel(const float* __restrict__ src,
                                                    uint16_t* __restrict__ dst,
                                                    int K, int N, int dstStride){
  __shared__ float tile[32][33];
  int t = threadIdx.x;
  int n0 = blockIdx.x<<5, k0 = blockIdx.y<<5;
  int r = t>>3, c4 = (t&7)<<2;
  float4 v = *(const float4*)&src[(size_t)(k0+r)*N + n0 + c4];
  tile[r][c4] = v.x; tile[r][c4+1] = v.y; tile[r][c4+2] = v.z; tile[r][c4+3] = v.w;
  __syncthreads();
  int n = t>>3, kc = (t&7)<<2;
  ushort4 o;
  o.x = f2bf(tile[kc  ][n]);
  o.y = f2bf(tile[kc+1][n]);
  o.z = f2bf(tile[kc+2][n]);
  o.w = f2bf(tile[kc+3][n]);
  *(ushort4*)&dst[(size_t)(n0+n)*dstStride + k0 + kc] = o;
}

// ---------------- LayerNorm + modulation -> bf16 h ----------------
__global__ __launch_bounds__(256) void ln_mod_kernel(const float* __restrict__ x,
                                                     const float* __restrict__ temb,
                                                     uint16_t* __restrict__ h){
  int s = blockIdx.x;
  int t = threadIdx.x;
  const float4* row = (const float4*)(x + (size_t)s*DIM);
  float4 v[3];
  float sum=0.f, ss=0.f;
  #pragma unroll
  for (int i=0;i<3;i++){
    v[i] = row[t + i*256];
    sum += v[i].x+v[i].y+v[i].z+v[i].w;
    ss  += v[i].x*v[i].x + v[i].y*v[i].y + v[i].z*v[i].z + v[i].w*v[i].w;
  }
  #pragma unroll
  for (int off=32; off; off>>=1){ sum += __shfl_xor(sum, off, 64); ss += __shfl_xor(ss, off, 64); }
  __shared__ float red[8];
  int lane = t&63, w = t>>6;
  if (lane==0){ red[w]=sum; red[w+4]=ss; }
  __syncthreads();
  sum = red[0]+red[1]+red[2]+red[3];
  ss  = red[4]+red[5]+red[6]+red[7];
  float mu = sum*(1.f/DIM);
  float var = ss*(1.f/DIM) - mu*mu;
  float rs = rsqrtf(var + 1e-6f);
  uint16_t* hrow = h + (size_t)s*DIM;
  #pragma unroll
  for (int i=0;i<3;i++){
    int c = (t + i*256)*4;
    float4 sc = *(const float4*)&temb[DIM + c];
    float4 sh = *(const float4*)&temb[c];
    ushort4 o;
    o.x = f2bf((v[i].x - mu)*rs*(1.f+sc.x) + sh.x);
    o.y = f2bf((v[i].y - mu)*rs*(1.f+sc.y) + sh.y);
    o.z = f2bf((v[i].z - mu)*rs*(1.f+sc.z) + sh.z);
    o.w = f2bf((v[i].w - mu)*rs*(1.f+sc.w) + sh.w);
    *(ushort4*)&hrow[c] = o;
  }
}

// ---------------- GEMM: C[M,N] = A[M,K] * BT[N,K]^T ----------------
// Double-buffered LDS, single barrier/iter, prefetch depth 1 (hides cold-B HBM latency).
// PW = supertile width in n-tiles (compile-time for cheap div).
// FINAL epilogue: out[idx] = resid[idx] + gate[col]*acc   (fp32 out)
template<int PW, bool OUT_BF16, bool FINAL>
__global__ __launch_bounds__(256,4) void gemm_bt_kernel(const uint16_t* __restrict__ A,
                                                        const uint16_t* __restrict__ BT,
                                                        void* __restrict__ Cout,
                                                        const float* __restrict__ resid,
                                                        const float* __restrict__ temb,
                                                        int M, int N, int K){
  __shared__ alignas(16) uint16_t As[2][128*32];
  __shared__ alignas(16) uint16_t Bs[2][128*32];
  const int mt = M>>7;
  int b = blockIdx.x;
  int per = mt*PW;
  int panel = b/per;
  int rem = b - panel*per;
  int nIdx = rem % PW, mIdx = rem / PW;
  size_t n0 = (size_t)(panel*PW + nIdx)<<7;
  size_t m0 = (size_t)mIdx<<7;
  int t = threadIdx.x, lane = t&63;
  int w = t>>6, wm = (w>>1)<<6, wn = (w&1)<<6;
  int lr = lane&15, lk = (lane>>4)<<3;
  const uint16_t* Ab = A + m0*(size_t)K;
  const uint16_t* Bb = BT + n0*(size_t)K;
  int c0 = t, c1 = t+256;
  const char* ga0 = (const char*)(Ab + (size_t)(c0>>2)*K) + ((c0&3)<<4);
  const char* ga1 = (const char*)(Ab + (size_t)(c1>>2)*K) + ((c1&3)<<4);
  const char* gb0 = (const char*)(Bb + (size_t)(c0>>2)*K) + ((c0&3)<<4);
  const char* gb1 = (const char*)(Bb + (size_t)(c1>>2)*K) + ((c1&3)<<4);
  char* la0 = (char*)As + c0*16; char* la1 = (char*)As + c1*16;   // +8192*buf
  char* lb0 = (char*)Bs + c0*16; char* lb1 = (char*)Bs + c1*16;
  // prologue: stage tile 0 into buffer 0
  gl_lds16(ga0, la0); gl_lds16(ga1, la1);
  gl_lds16(gb0, lb0); gl_lds16(gb1, lb1);
  ga0 += 64; ga1 += 64; gb0 += 64; gb1 += 64;
  f32x4 acc[4][4] = {};
  int cur = 0;
  for (int k0=0; k0<K; k0+=32){
    __syncthreads();   // buf[cur] loads drained; all frag reads of buf[cur^1] complete
    if (k0 + 32 < K){
      int nb = cur^1;
      gl_lds16(ga0, la0 + nb*8192); gl_lds16(ga1, la1 + nb*8192);
      gl_lds16(gb0, lb0 + nb*8192); gl_lds16(gb1, lb1 + nb*8192);
      ga0 += 64; ga1 += 64; gb0 += 64; gb1 += 64;
    }
    const uint16_t* Ac = As[cur];
    const uint16_t* Bc = Bs[cur];
    short8 af[4], bf[4];
    #pragma unroll
    for (int mi=0;mi<4;mi++) af[mi] = *(const short8*)&Ac[(wm + mi*16 + lr)*32 + lk];
    #pragma unroll
    for (int ni=0;ni<4;ni++) bf[ni] = *(const short8*)&Bc[(wn + ni*16 + lr)*32 + lk];
    #pragma unroll
    for (int mi=0;mi<4;mi++)
      #pragma unroll
      for (int ni=0;ni<4;ni++)
        acc[mi][ni] = __builtin_amdgcn_mfma_f32_16x16x32_bf16(af[mi], bf[ni], acc[mi][ni], 0,0,0);
    cur ^= 1;
  }
  int qr = (lane>>4)<<2;
  #pragma unroll
  for (int mi=0;mi<4;mi++)
    #pragma unroll
    for (int ni=0;ni<4;ni++){
      size_t col = n0 + wn + ni*16 + lr;
      #pragma unroll
      for (int r=0;r<4;r++){
        size_t row = m0 + wm + mi*16 + qr + r;
        size_t idx = row*(size_t)N + col;
        float vv = acc[mi][ni][r];
        if (FINAL) vv = resid[idx] + temb[2*DIM + col]*vv;
        if (OUT_BF16) ((uint16_t*)Cout)[idx] = f2bf(vv);
        else          ((float*)Cout)[idx] = vv;
      }
    }
}

// ---------------- per-head RMSNorm + RoPE on q,k (in place) ----------------
__global__ __launch_bounds__(256) void qk_rope_kernel(uint16_t* __restrict__ qkv,
                                                      const float* __restrict__ cosb,
                                                      const float* __restrict__ sinb,
                                                      const float* __restrict__ wq,
                                                      const float* __restrict__ wk){
  int t = threadIdx.x, lane = t&63, w = t>>6;
  int pair = blockIdx.x*4 + w;
  int s = pair/24, hh = pair - s*24;
  int d0 = lane*2;
  float c0 = cosb[s*HD + d0], c1 = cosb[s*HD + d0+1];
  float sn0 = sinb[s*HD + d0], sn1 = sinb[s*HD + d0+1];
  #pragma unroll
  for (int which=0; which<2; ++which){
    uint16_t* p = qkv + (size_t)s*SD + which*DIM + hh*HD + d0;
    const float* ww = which ? wk : wq;
    uint32_t u = *(const uint32_t*)p;
    float x0 = bf2f((uint16_t)(u&0xffffu)), x1 = bf2f((uint16_t)(u>>16));
    float ssum = x0*x0 + x1*x1;
    #pragma unroll
    for (int off=32; off; off>>=1) ssum += __shfl_xor(ssum, off, 64);
    float r = rsqrtf(ssum*(1.f/HD) + 1e-6f);
    float xn0 = x0*r*ww[d0], xn1 = x1*r*ww[d0+1];
    float y0 = xn0*c0 - xn1*sn0;
    float y1 = xn1*c1 + xn0*sn1;
    *(uint32_t*)p = (uint32_t)f2bf(y0) | ((uint32_t)f2bf(y1)<<16);
  }
}

// ---------------- flash attention (out has row stride K2, cols 0..DIM-1) ----------------
__global__ __launch_bounds__(256) void attn_kernel(const uint16_t* __restrict__ qkv,
                                                   uint16_t* __restrict__ out){
  __shared__ alignas(16) uint16_t QP[64*128];   // Q staging, then per-wave P (swizzled)
  __shared__ alignas(16) uint16_t Ks[64*128];   // [key][d], d-granule swizzled by key&15
  __shared__ alignas(16) uint16_t Vt[128*64];   // [d][key], key-granule swizzled by (d>>1)&7
  int t = threadIdx.x, lane = t&63, w = t>>6;
  int q0 = blockIdx.x<<6, h = blockIdx.y;
  int lr = lane&15, q4 = lane>>4, lk = q4<<3;
  const uint16_t* qb = qkv + (size_t)q0*SD + h*HD;
  #pragma unroll
  for (int i=0;i<4;i++){
    int c = t + i*256;
    gl_lds16((const char*)(qb + (size_t)(c>>4)*SD) + ((c&15)<<4), (char*)QP + c*16);
  }
  __syncthreads();
  short8 qf[4];
  #pragma unroll
  for (int kc=0;kc<4;kc++) qf[kc] = *(const short8*)&QP[(w*16+lr)*128 + kc*32 + lk];
  __syncthreads();   // QP now reusable as P scratch
  float m_i[4] = {-3.0e38f,-3.0e38f,-3.0e38f,-3.0e38f};
  float l_i[4] = {0.f,0.f,0.f,0.f};
  f32x4 o[8] = {};
  const uint16_t* kb = qkv + (size_t)DIM + h*HD;
  const uint16_t* vb = qkv + (size_t)(2*DIM) + h*HD;
  uint16_t* Pw = QP + w*(16*64);
  const float scale = 0.08838834764831845f;
  for (int kt=0; kt<64; ++kt){
    const uint16_t* kbt = kb + (size_t)(kt<<6)*SD;
    const uint16_t* vbt = vb + (size_t)(kt<<6)*SD;
    __syncthreads();
    #pragma unroll
    for (int i=0;i<4;i++){          // K tile, swizzled
      int c = t + i*256;
      int row = c>>4, gd = c&15;
      uint4 vv = *(const uint4*)(kbt + (size_t)row*SD + gd*8);
      *(uint4*)&Ks[row*128 + ((gd ^ (row&15))<<3)] = vv;
    }
    #pragma unroll
    for (int i=0;i<8;i++){          // V tile, transposed + swizzled
      int idx = t + i*256;
      int rp = idx>>6;
      int k0 = rp<<1, d0 = lane<<1;
      uint32_t u0 = *(const uint32_t*)(vbt + (size_t)k0*SD + d0);
      uint32_t u1 = *(const uint32_t*)(vbt + (size_t)(k0+1)*SD + d0);
      int pos = (((rp>>2) ^ (lane&7))<<3) + (k0&7);
      *(uint32_t*)&Vt[(d0<<6) + pos]     = (u0&0xffffu) | (u1<<16);
      *(uint32_t*)&Vt[((d0+1)<<6) + pos] = (u0>>16) | (u1&0xffff0000u);
    }
    __syncthreads();
    f32x4 sa[4];
    #pragma unroll
    for (int nk=0;nk<4;nk++){
      sa[nk] = (f32x4){0.f,0.f,0.f,0.f};
      #pragma unroll
      for (int kc=0;kc<4;kc++){
        short8 kf = *(const short8*)&Ks[(nk*16+lr)*128 + (((kc*4+q4) ^ lr)<<3)];
        sa[nk] = __builtin_amdgcn_mfma_f32_16x16x32_bf16(qf[kc], kf, sa[nk], 0,0,0);
      }
      sa[nk] *= scale;
    }
    float alpha[4], psum[4];
    #pragma unroll
    for (int r=0;r<4;r++){
      float mx = fmaxf(fmaxf(sa[0][r], sa[1][r]), fmaxf(sa[2][r], sa[3][r]));
      mx = fmaxf(mx, __shfl_xor(mx, 1, 64));
      mx = fmaxf(mx, __shfl_xor(mx, 2, 64));
      mx = fmaxf(mx, __shfl_xor(mx, 4, 64));
      mx = fmaxf(mx, __shfl_xor(mx, 8, 64));
      float mn = fmaxf(m_i[r], mx);
      alpha[r] = __expf(m_i[r] - mn);
      m_i[r] = mn;
      psum[r] = 0.f;
    }
    int prow = q4<<2;
    #pragma unroll
    for (int nk=0;nk<4;nk++){
      #pragma unroll
      for (int r=0;r<4;r++){
        float p = __expf(sa[nk][r] - m_i[r]);
        psum[r] += p;
        int key = nk*16 + lr;
        Pw[(prow+r)*64 + ((((key>>3) ^ (prow+r))&7)<<3) + (key&7)] = f2bf(p);
      }
    }
    #pragma unroll
    for (int r=0;r<4;r++){
      float ps = psum[r];
      ps += __shfl_xor(ps, 1, 64);
      ps += __shfl_xor(ps, 2, 64);
      ps += __shfl_xor(ps, 4, 64);
      ps += __shfl_xor(ps, 8, 64);
      l_i[r] = l_i[r]*alpha[r] + ps;
    }
    #pragma unroll
    for (int nd=0;nd<8;nd++){
      f32x4 t4 = o[nd];
      t4[0]*=alpha[0]; t4[1]*=alpha[1]; t4[2]*=alpha[2]; t4[3]*=alpha[3];
      o[nd]=t4;
    }
    #pragma unroll
    for (int kc=0;kc<2;kc++){
      short8 pf = *(const short8*)&Pw[lr*64 + ((((kc*4+q4) ^ lr)&7)<<3)];
      #pragma unroll
      for (int nd=0;nd<8;nd++){
        int d = nd*16 + lr;
        short8 vf = *(const short8*)&Vt[(d<<6) + ((((kc*4+q4) ^ ((lr>>1)&7)))<<3)];
        o[nd] = __builtin_amdgcn_mfma_f32_16x16x32_bf16(pf, vf, o[nd], 0,0,0);
      }
    }
  }
  uint16_t* ob = out + (size_t)(q0 + w*16)*K2 + h*HD;
  #pragma unroll
  for (int r=0;r<4;r++){
    float inv = 1.f/l_i[r];
    #pragma unroll
    for (int nd=0;nd<8;nd++)
      ob[(size_t)(q4*4 + r)*K2 + nd*16 + lr] = f2bf(o[nd][r]*inv);
  }
}

// ---------------- SwiGLU (out has row stride K2, at col offset DIM) ----------------
__global__ __launch_bounds__(256) void swiglu_kernel(const uint16_t* __restrict__ qkv,
                                                     uint16_t* __restrict__ mlp){
  size_t idx = ((size_t)blockIdx.x*256 + threadIdx.x)*4;
  size_t s = idx/MLP, j = idx - s*MLP;
  const uint16_t* pa = qkv + s*SD + 3*DIM + j;
  const uint16_t* pb = pa + MLP;
  ushort4 ua = *(const ushort4*)pa, ub = *(const ushort4*)pb;
  ushort4 o;
  float a, b;
  a = bf2f(ua.x); b = bf2f(ub.x); o.x = f2bf(a*b/(1.f+__expf(-a)));
  a = bf2f(ua.y); b = bf2f(ub.y); o.y = f2bf(a*b/(1.f+__expf(-a)));
  a = bf2f(ua.z); b = bf2f(ub.z); o.z = f2bf(a*b/(1.f+__expf(-a)));
  a = bf2f(ua.w); b = bf2f(ub.w); o.w = f2bf(a*b/(1.f+__expf(-a)));
  *(ushort4*)(mlp + s*K2 + j) = o;
}

extern "C" void kernel_launch(void* const* d_in, const int* in_sizes, int n_in,
                              void* d_out, int out_size, void* d_ws, size_t ws_size,
                              hipStream_t stream){
  (void)in_sizes; (void)n_in; (void)out_size;
  const float* hs   = (const float*)d_in[0];
  const float* temb = (const float*)d_in[1];
  const float* rcos = (const float*)d_in[2];
  const float* rsin = (const float*)d_in[3];
  const float* w1   = (const float*)d_in[4];
  const float* wa   = (const float*)d_in[5];
  const float* wm   = (const float*)d_in[6];
  const float* nqw  = (const float*)d_in[7];
  const float* nkw  = (const float*)d_in[8];

  char* ws = (char*)d_ws;
  const size_t off_w1T  = 0;               // 27648x3072 bf16 = 169,869,312
  const size_t off_woT  = 169869312ULL;    // 3072x12288 bf16 =  75,497,472
  const size_t off_h    = 245366784ULL;    // 4096x3072  bf16 =  25,165,824
  const size_t off_qkv  = 270532608ULL;    // 4096x27648 bf16 = 226,492,416
  const size_t off_ap   = 497025024ULL;    // 4096x12288 bf16 = 100,663,296
  const size_t needed   = 597688320ULL;
  if (ws_size < needed) return;

  uint16_t* w1T  = (uint16_t*)(ws + off_w1T);
  uint16_t* woT  = (uint16_t*)(ws + off_woT);
  uint16_t* hbuf = (uint16_t*)(ws + off_h);
  uint16_t* qkv  = (uint16_t*)(ws + off_qkv);
  uint16_t* ap   = (uint16_t*)(ws + off_ap);   // [attn | swiglu] fused A'

  castT_kernel<<<dim3(FUSED/32, DIM/32), 256, 0, stream>>>(w1, w1T, DIM, FUSED, DIM);
  castT_kernel<<<dim3(DIM/32,  DIM/32),  256, 0, stream>>>(wa, woT, DIM, DIM, K2);
  castT_kernel<<<dim3(DIM/32,  MLP/32),  256, 0, stream>>>(wm, woT + DIM, MLP, DIM, K2);
  ln_mod_kernel<<<SEQ, 256, 0, stream>>>(hs, temb, hbuf);
  gemm_bt_kernel<24,true,false><<<(SEQ/128)*(FUSED/128), 256, 0, stream>>>(hbuf, w1T, qkv, nullptr, nullptr, SEQ, FUSED, DIM);
  qk_rope_kernel<<<SEQ*NH/4, 256, 0, stream>>>(qkv, rcos, rsin, nqw, nkw);
  attn_kernel<<<dim3(SEQ/64, NH), 256, 0, stream>>>(qkv, ap);
  swiglu_kernel<<<(SEQ*(size_t)MLP/4)/256, 256, 0, stream>>>(qkv, ap + DIM);
  gemm_bt_kernel<24,false,true><<<(SEQ/128)*(DIM/128), 256, 0, stream>>>(ap, woT, d_out, hs, temb, SEQ, DIM, K2);
}